// Round 1
// baseline (247.856 us; speedup 1.0000x reference)
//
#include <hip/hip_runtime.h>

typedef unsigned short u16;
typedef float f32x4 __attribute__((ext_vector_type(4)));
typedef short s16x8 __attribute__((ext_vector_type(8)));

#define B_ 2
#define N_ 2048
#define C_ 1024
#define H_ 16
#define BN_ (B_*N_)   // 4096 rows

// ---------- helpers ----------
__device__ __forceinline__ u16 f2bf(float f) {
  union { float f; unsigned u; } c; c.f = f;
  unsigned u = c.u;
  u = (u + 0x7fffu + ((u >> 16) & 1u)) >> 16;   // RNE
  return (u16)u;
}
__device__ __forceinline__ float bf2f(u16 h) {
  union { unsigned u; float f; } c; c.u = ((unsigned)h) << 16;
  return c.f;
}
__device__ __forceinline__ void gload16(const u16* g, u16* l) {
  __builtin_amdgcn_global_load_lds(
      (const __attribute__((address_space(1))) unsigned*)g,
      (__attribute__((address_space(3))) unsigned*)l, 16, 0, 0);
}

// ---------- fp32 -> bf16 cast (vectorized) ----------
__global__ __launch_bounds__(256) void k_cast_bf16(const float* __restrict__ x,
                                                   u16* __restrict__ o, int n4) {
  int i = blockIdx.x * blockDim.x + threadIdx.x;
  if (i >= n4) return;
  float4 v = ((const float4*)x)[i];
  ushort4 r;
  r.x = f2bf(v.x); r.y = f2bf(v.y); r.z = f2bf(v.z); r.w = f2bf(v.w);
  ((ushort4*)o)[i] = r;
}

// ---------- fp32 [R][C] -> bf16 [C][R] transpose+cast ----------
__global__ __launch_bounds__(256) void k_transpose_cast(const float* __restrict__ W,
                                                        u16* __restrict__ Wt,
                                                        int R, int Cc) {
  __shared__ float t[32][33];
  int tx = threadIdx.x, ty = threadIdx.y;
  int c0 = blockIdx.x * 32, r0 = blockIdx.y * 32;
#pragma unroll
  for (int i = 0; i < 4; ++i)
    t[ty + i * 8][tx] = W[(long)(r0 + ty + i * 8) * Cc + c0 + tx];
  __syncthreads();
#pragma unroll
  for (int i = 0; i < 4; ++i)
    Wt[(long)(c0 + ty + i * 8) * R + r0 + tx] = f2bf(t[tx][ty + i * 8]);
}

// ---------- GEMM: C[M][N] = A[M][K](bf16) * Bt[N][K](bf16)^T  (m97-style) ----------
// MODE 0: output bf16, no bias.  MODE 1: output fp32 + bias.
template <int MODE>
__global__ __launch_bounds__(256) void k_gemm_bt(const u16* __restrict__ A,
                                                 const u16* __restrict__ Bt,
                                                 void* __restrict__ Cout,
                                                 const float* __restrict__ bias,
                                                 int M, int N, int K) {
  __shared__ u16 a_t[128 * 64];
  __shared__ u16 b_t[128 * 64];
  int tid = threadIdx.x;
  int w = tid >> 6, l = tid & 63;
  int l15 = l & 15, lhi = l >> 4;
  int wm = w >> 1, wn = w & 1;
  int rowA = l >> 3, colA = (l & 7) * 8;
  const u16* Ab = A + (long)blockIdx.y * 128 * K;
  const u16* Bb = Bt + (long)blockIdx.x * 128 * K;
  f32x4 acc[4][4];
#pragma unroll
  for (int m = 0; m < 4; ++m)
#pragma unroll
    for (int n = 0; n < 4; ++n)
      acc[m][n] = (f32x4){0.f, 0.f, 0.f, 0.f};

  for (int k0 = 0; k0 < K; k0 += 64) {
#pragma unroll
    for (int i = 0; i < 4; ++i) {
      int ci = i * 4 + w;
      gload16(Ab + (long)(ci * 8 + rowA) * K + k0 + colA, &a_t[ci * 8 * 64]);
      gload16(Bb + (long)(ci * 8 + rowA) * K + k0 + colA, &b_t[ci * 8 * 64]);
    }
    __syncthreads();
#pragma unroll
    for (int kk = 0; kk < 2; ++kk) {
      s16x8 af[4], bfr[4];
#pragma unroll
      for (int m = 0; m < 4; ++m)
        af[m] = *(const s16x8*)&a_t[(wm * 64 + m * 16 + l15) * 64 + kk * 32 + lhi * 8];
#pragma unroll
      for (int n = 0; n < 4; ++n)
        bfr[n] = *(const s16x8*)&b_t[(wn * 64 + n * 16 + l15) * 64 + kk * 32 + lhi * 8];
#pragma unroll
      for (int m = 0; m < 4; ++m)
#pragma unroll
        for (int n = 0; n < 4; ++n)
          acc[m][n] = __builtin_amdgcn_mfma_f32_16x16x32_bf16(af[m], bfr[n], acc[m][n], 0, 0, 0);
    }
    __syncthreads();
  }
#pragma unroll
  for (int m = 0; m < 4; ++m) {
#pragma unroll
    for (int n = 0; n < 4; ++n) {
      int col = blockIdx.x * 128 + wn * 64 + n * 16 + l15;
#pragma unroll
      for (int r = 0; r < 4; ++r) {
        int row = blockIdx.y * 128 + wm * 64 + m * 16 + lhi * 4 + r;
        float v = acc[m][n][r];
        if (MODE == 1)
          ((float*)Cout)[(long)row * N + col] = v + bias[col];
        else
          ((u16*)Cout)[(long)row * N + col] = f2bf(v);
      }
    }
  }
}

// ---------- LayerNorm(Dh=64) on q,k + split/transpose to [B*H][N][64] ----------
__global__ __launch_bounds__(256) void k_ln_split(const u16* __restrict__ qkvb,
                                                  const float* __restrict__ qg,
                                                  const float* __restrict__ qbeta,
                                                  const float* __restrict__ kg,
                                                  const float* __restrict__ kbeta,
                                                  u16* __restrict__ Qh,
                                                  u16* __restrict__ Kh,
                                                  u16* __restrict__ Vh) {
  int wid = threadIdx.x >> 6, l = threadIdx.x & 63;
  const long nrows = (long)BN_ * 3 * H_;  // 196608 rows of 64
  for (long row = (long)blockIdx.x * 4 + wid; row < nrows; row += (long)gridDim.x * 4) {
    float v = bf2f(qkvb[row * 64 + l]);
    int h = (int)(row & 15);
    long t1 = row >> 4;           // (b*N+n)*3 + s
    int s = (int)(t1 % 3);
    long bn = t1 / 3;             // b*N + n
    long orow = ((bn >> 11) * H_ + h) * (long)N_ + (bn & (N_ - 1));
    if (s == 2) {
      Vh[orow * 64 + l] = f2bf(v);
      continue;
    }
    float m = v;
#pragma unroll
    for (int o = 1; o < 64; o <<= 1) m += __shfl_xor(m, o);
    m *= (1.f / 64.f);
    float d = v - m;
    float va = d * d;
#pragma unroll
    for (int o = 1; o < 64; o <<= 1) va += __shfl_xor(va, o);
    va *= (1.f / 64.f);
    float rs = rsqrtf(va + 1e-6f);
    float y = (s == 0) ? (qg[l] * d * rs + qbeta[l]) : (kg[l] * d * rs + kbeta[l]);
    u16* O = (s == 0) ? Qh : Kh;
    O[orow * 64 + l] = f2bf(y);
  }
}

// ---------- V [bh][N][64] -> Vt [bh][64][N] (bf16 transpose) ----------
__global__ __launch_bounds__(512) void k_transpose_v(const u16* __restrict__ Vh,
                                                     u16* __restrict__ Vt) {
  __shared__ u16 t[64][65];
  int tx = threadIdx.x, ty = threadIdx.y;  // (64,8)
  int bh = blockIdx.y;
  int n0 = blockIdx.x * 64;
#pragma unroll
  for (int i = 0; i < 8; ++i)
    t[ty + i * 8][tx] = Vh[((long)bh * N_ + n0 + ty + i * 8) * 64 + tx];
  __syncthreads();
#pragma unroll
  for (int i = 0; i < 8; ++i)
    Vt[((long)bh * 64 + ty + i * 8) * N_ + n0 + tx] = t[tx][ty + i * 8];
}

// ---------- flash attention ----------
// Qh,Kh: [bh][N][64] bf16 (LN'd), Vt: [bh][64][N] bf16, O: [B][N][H*64] bf16
__global__ __launch_bounds__(256) void k_attn(const u16* __restrict__ Qh,
                                              const u16* __restrict__ Kh,
                                              const u16* __restrict__ Vt,
                                              u16* __restrict__ O) {
  __shared__ u16 k_t[128 * 64];
  __shared__ u16 v_t[64 * 128];
  __shared__ u16 p_t[128 * 128];
  int tid = threadIdx.x;
  int w = tid >> 6, l = tid & 63;
  int l15 = l & 15, lhi = l >> 4;
  int qb = blockIdx.x, bh = blockIdx.y;
  int b = bh >> 4, h = bh & 15;
  const u16* Qb = Qh + ((long)bh * N_ + qb * 128) * 64;
  const u16* Kb = Kh + (long)bh * N_ * 64;
  const u16* Vb = Vt + (long)bh * 64 * N_;

  // hoist Q fragments to registers
  s16x8 qf[2][2];
#pragma unroll
  for (int mf = 0; mf < 2; ++mf)
#pragma unroll
    for (int kk = 0; kk < 2; ++kk)
      qf[mf][kk] = *(const s16x8*)&Qb[(long)(w * 32 + mf * 16 + l15) * 64 + kk * 32 + lhi * 8];

  f32x4 acc[2][4];
#pragma unroll
  for (int mf = 0; mf < 2; ++mf)
#pragma unroll
    for (int nd = 0; nd < 4; ++nd) acc[mf][nd] = (f32x4){0.f, 0.f, 0.f, 0.f};
  float mrow[2][4], lrow[2][4];
#pragma unroll
  for (int mf = 0; mf < 2; ++mf)
#pragma unroll
    for (int r = 0; r < 4; ++r) { mrow[mf][r] = -3e38f; lrow[mf][r] = 0.f; }

  int rowK = l >> 3, colK = (l & 7) * 8;
  int rowV = l >> 4, colV = (l & 15) * 8;

  for (int t = 0; t < N_ / 128; ++t) {
    int kt = t * 128;
#pragma unroll
    for (int i = 0; i < 4; ++i) {
      int ci = i * 4 + w;
      gload16(Kb + (long)(kt + ci * 8 + rowK) * 64 + colK, &k_t[ci * 8 * 64]);
      gload16(Vb + (long)(ci * 4 + rowV) * N_ + kt + colV, &v_t[ci * 4 * 128]);
    }
    __syncthreads();

    // S = Q K^T
    f32x4 s[2][8];
#pragma unroll
    for (int mf = 0; mf < 2; ++mf)
#pragma unroll
      for (int nf = 0; nf < 8; ++nf) s[mf][nf] = (f32x4){0.f, 0.f, 0.f, 0.f};
#pragma unroll
    for (int nf = 0; nf < 8; ++nf) {
#pragma unroll
      for (int kk = 0; kk < 2; ++kk) {
        s16x8 kfrag = *(const s16x8*)&k_t[(nf * 16 + l15) * 64 + kk * 32 + lhi * 8];
        s[0][nf] = __builtin_amdgcn_mfma_f32_16x16x32_bf16(qf[0][kk], kfrag, s[0][nf], 0, 0, 0);
        s[1][nf] = __builtin_amdgcn_mfma_f32_16x16x32_bf16(qf[1][kk], kfrag, s[1][nf], 0, 0, 0);
      }
    }

    // online softmax (row = mf*16 + lhi*4 + r ; col = nf*16 + l15)
#pragma unroll
    for (int mf = 0; mf < 2; ++mf) {
#pragma unroll
      for (int r = 0; r < 4; ++r) {
        float mx = -3e38f;
#pragma unroll
        for (int nf = 0; nf < 8; ++nf) {
          float sv = s[mf][nf][r] * 0.125f;
          s[mf][nf][r] = sv;
          mx = fmaxf(mx, sv);
        }
#pragma unroll
        for (int o = 1; o < 16; o <<= 1) mx = fmaxf(mx, __shfl_xor(mx, o));
        float mnew = fmaxf(mrow[mf][r], mx);
        float alpha = __expf(mrow[mf][r] - mnew);
        mrow[mf][r] = mnew;
        float rsum = 0.f;
#pragma unroll
        for (int nf = 0; nf < 8; ++nf) {
          float p = __expf(s[mf][nf][r] - mnew);
          s[mf][nf][r] = p;
          rsum += p;
        }
#pragma unroll
        for (int o = 1; o < 16; o <<= 1) rsum += __shfl_xor(rsum, o);
        lrow[mf][r] = lrow[mf][r] * alpha + rsum;
#pragma unroll
        for (int nd = 0; nd < 4; ++nd) acc[mf][nd][r] *= alpha;
      }
    }

    // P -> LDS (bf16)
#pragma unroll
    for (int mf = 0; mf < 2; ++mf)
#pragma unroll
      for (int nf = 0; nf < 8; ++nf)
#pragma unroll
        for (int r = 0; r < 4; ++r)
          p_t[(w * 32 + mf * 16 + lhi * 4 + r) * 128 + nf * 16 + l15] = f2bf(s[mf][nf][r]);
    __syncthreads();  // cross-lane LDS exchange: order P-writes before P-reads

    // O += P V
#pragma unroll
    for (int kf = 0; kf < 4; ++kf) {
      s16x8 pa[2];
#pragma unroll
      for (int mf = 0; mf < 2; ++mf)
        pa[mf] = *(const s16x8*)&p_t[(w * 32 + mf * 16 + l15) * 128 + kf * 32 + lhi * 8];
#pragma unroll
      for (int nd = 0; nd < 4; ++nd) {
        s16x8 vb = *(const s16x8*)&v_t[(nd * 16 + l15) * 128 + kf * 32 + lhi * 8];
        acc[0][nd] = __builtin_amdgcn_mfma_f32_16x16x32_bf16(pa[0], vb, acc[0][nd], 0, 0, 0);
        acc[1][nd] = __builtin_amdgcn_mfma_f32_16x16x32_bf16(pa[1], vb, acc[1][nd], 0, 0, 0);
      }
    }
    __syncthreads();
  }

  // epilogue: O[b][q][h*64+d] = acc / l
#pragma unroll
  for (int mf = 0; mf < 2; ++mf) {
#pragma unroll
    for (int r = 0; r < 4; ++r) {
      float inv = 1.f / lrow[mf][r];
      int q = qb * 128 + w * 32 + mf * 16 + lhi * 4 + r;
#pragma unroll
      for (int nd = 0; nd < 4; ++nd) {
        int d = nd * 16 + l15;
        O[((long)(b * N_ + q) * H_ + h) * 64 + d] = f2bf(acc[mf][nd][r] * inv);
      }
    }
  }
}

// ---------- launch ----------
extern "C" void kernel_launch(void* const* d_in, const int* in_sizes, int n_in,
                              void* d_out, int out_size, void* d_ws, size_t ws_size,
                              hipStream_t stream) {
  const float* x      = (const float*)d_in[0];
  const float* qkv_w  = (const float*)d_in[1];
  const float* q_g    = (const float*)d_in[2];
  const float* q_b    = (const float*)d_in[3];
  const float* k_g    = (const float*)d_in[4];
  const float* k_b    = (const float*)d_in[5];
  const float* proj_w = (const float*)d_in[6];
  const float* proj_b = (const float*)d_in[7];
  float* out = (float*)d_out;

  char* ws = (char*)d_ws;
  // byte offsets (all 256-aligned)
  u16* xb     = (u16*)(ws + 0);                       //  8 MB  [4096][1024]
  u16* wqkvT  = (u16*)(ws + 8388608);                 //  6 MB  [3072][1024]
  u16* wprojT = (u16*)(ws + 14680064);                //  2 MB  [1024][1024]
  u16* qkvb   = (u16*)(ws + 16777216);                // 24 MB  [4096][3072]
  u16* Qh     = (u16*)(ws + 41943040);                //  8 MB  [32][2048][64]
  u16* Kh     = (u16*)(ws + 50331648);                //  8 MB
  u16* Vh     = (u16*)(ws + 58720256);                //  8 MB
  u16* Vt     = (u16*)(ws + 67108864);                //  8 MB  [32][64][2048]
  u16* attnO  = xb;                                   // reuse (xb dead after QKV GEMM)

  k_cast_bf16<<<4096, 256, 0, stream>>>(x, xb, (BN_ * C_) / 4);
  k_transpose_cast<<<dim3(96, 32), dim3(32, 8), 0, stream>>>(qkv_w, wqkvT, C_, 3 * C_);
  k_transpose_cast<<<dim3(32, 32), dim3(32, 8), 0, stream>>>(proj_w, wprojT, C_, C_);
  k_gemm_bt<0><<<dim3(24, 32), 256, 0, stream>>>(xb, wqkvT, qkvb, nullptr, BN_, 3 * C_, C_);
  k_ln_split<<<2048, 256, 0, stream>>>(qkvb, q_g, q_b, k_g, k_b, Qh, Kh, Vh);
  k_transpose_v<<<dim3(32, 32), dim3(64, 8), 0, stream>>>(Vh, Vt);
  k_attn<<<dim3(16, 32), 256, 0, stream>>>(Qh, Kh, Vt, attnO);
  k_gemm_bt<1><<<dim3(8, 32), 256, 0, stream>>>(attnO, wprojT, out, proj_b, BN_, C_, C_);
}